// Round 9
// baseline (361.156 us; speedup 1.0000x reference)
//
#include <hip/hip_runtime.h>

#define B_ 8
#define NN 4096
#define C_ 256
#define CK_ 32

typedef __attribute__((ext_vector_type(8))) short bf16x8;
typedef __attribute__((ext_vector_type(4))) float f32x4;
typedef __attribute__((ext_vector_type(4))) unsigned int u32x4;

typedef const __attribute__((address_space(1))) void* gas_ptr;
typedef __attribute__((address_space(3))) void* las_ptr;

__device__ __forceinline__ void gload16(const void* src, void* dst) {
    __builtin_amdgcn_global_load_lds((gas_ptr)src, (las_ptr)dst, 16, 0, 0);
}
__device__ __forceinline__ ushort bf16_rne(float v) {
    unsigned u = __builtin_bit_cast(unsigned, v);
    unsigned r = (u + 0x7fffu + ((u >> 16) & 1u)) >> 16;
    return (ushort)r;
}
__device__ __forceinline__ float bf16_to_f(ushort h) {
    return __builtin_bit_cast(float, (unsigned)h << 16);
}
#define MFMA16 __builtin_amdgcn_mfma_f32_16x16x32_bf16

// ---------------- Kernel 0: pack W -> bf16 hi/lo MFMA fragments --------------
__global__ __launch_bounds__(256) void prep_kernel(
    const float* __restrict__ Wf, const float* __restrict__ Wg,
    const float* __restrict__ Wh,
    ushort* __restrict__ whi, ushort* __restrict__ wlo)
{
    const int idx = blockIdx.x * 256 + threadIdx.x;   // grid = 320 blocks
    const int e = idx & 7, ll = (idx >> 3) & 63, kc = (idx >> 9) & 7, ct = idx >> 12;
    const int k = kc * 32 + (ll >> 4) * 8 + e;
    const int a = ll & 15;
    float v;
    if (ct < 2)      v = Wf[k * 32 + ct * 16 + a];
    else if (ct < 4) v = Wg[k * 32 + (ct - 2) * 16 + a];
    else             v = Wh[k * 256 + (ct - 4) * 16 + a];
    const ushort hi = bf16_rne(v);
    whi[idx] = hi;
    wlo[idx] = bf16_rne(v - bf16_to_f(hi));
}

// ---------------- Kernel 1: MFMA projections, ct-split waves -----------------
// 512 blocks x 64 rows. Wave w owns 5 output col-tiles over ALL 64 rows
// (4 row-groups): each W-fragment load feeds 12 MFMAs (was 3).
// x converted ONCE to swizzled bf16 hi/lo in LDS.
__global__ __launch_bounds__(256, 2) void proj_kernel(
    const float* __restrict__ x,
    const ushort* __restrict__ whi, const ushort* __restrict__ wlo,
    const float* __restrict__ bfp, const float* __restrict__ bgp,
    const float* __restrict__ bhp,
    ushort* __restrict__ fh, ushort* __restrict__ fl,
    ushort* __restrict__ gh, ushort* __restrict__ gl,
    ushort* __restrict__ ht)
{
    __shared__ __align__(16) ushort sbuf[32768];  // xh [0,16384), xl [16384,32768); hs aliases [0,20480)
    const int tid = threadIdx.x, l = tid & 63, wv = tid >> 6;
    const int g = l >> 4, a = l & 15;
    const int rowbase = blockIdx.x * 64;
    const int bb = rowbase >> 12, n0 = rowbase & 4095;

    // ---- stage x -> bf16 hi/lo in LDS, T2-swizzled (byte ^= (row&7)<<4)
    {
        const int r = tid >> 2, cq = tid & 3;
        const float* xrow = x + (size_t)(rowbase + r) * 256;
        const unsigned swz = (unsigned)((r & 7) << 4);
#pragma unroll
        for (int j = 0; j < 16; j++) {
            float4 v = *(const float4*)&xrow[cq * 4 + j * 16];
            ushort h0 = bf16_rne(v.x), h1 = bf16_rne(v.y);
            ushort h2 = bf16_rne(v.z), h3 = bf16_rne(v.w);
            uint2 hw, lw;
            hw.x = (unsigned)h0 | ((unsigned)h1 << 16);
            hw.y = (unsigned)h2 | ((unsigned)h3 << 16);
            lw.x = (unsigned)bf16_rne(v.x - bf16_to_f(h0)) |
                   ((unsigned)bf16_rne(v.y - bf16_to_f(h1)) << 16);
            lw.y = (unsigned)bf16_rne(v.z - bf16_to_f(h2)) |
                   ((unsigned)bf16_rne(v.w - bf16_to_f(h3)) << 16);
            const unsigned byt = (unsigned)(r * 512 + cq * 8 + j * 32) ^ swz;
            *(uint2*)&sbuf[byt >> 1] = hw;
            *(uint2*)&sbuf[16384 + (byt >> 1)] = lw;
        }
    }
    __syncthreads();

    // ---- compute: 5 col-tiles x 8 k-chunks x 4 row-groups, 3-term hi/lo
    f32x4 acc[5][4];
#pragma unroll
    for (int ci = 0; ci < 5; ci++)
#pragma unroll
        for (int rg = 0; rg < 4; rg++) acc[ci][rg] = (f32x4){0.f, 0.f, 0.f, 0.f};

#pragma unroll
    for (int ci = 0; ci < 5; ci++) {
        const int ct = wv * 5 + ci;
#pragma unroll
        for (int kc = 0; kc < 8; kc++) {
            const size_t fo = (size_t)((ct * 8 + kc) * 64 + l) * 8;
            const bf16x8 wh = *(const bf16x8*)(whi + fo);
            const bf16x8 wl = *(const bf16x8*)(wlo + fo);
#pragma unroll
            for (int rg = 0; rg < 4; rg++) {
                const unsigned byt = (unsigned)((rg * 16 + a) * 512 + kc * 64 + g * 16)
                                     ^ (unsigned)((a & 7) << 4);
                const bf16x8 xhf = *(const bf16x8*)&sbuf[byt >> 1];
                const bf16x8 xlf = *(const bf16x8*)&sbuf[16384 + (byt >> 1)];
                if (ct < 4) {   // D[wcol][xrow]
                    acc[ci][rg] = MFMA16(wh, xhf, acc[ci][rg], 0, 0, 0);
                    acc[ci][rg] = MFMA16(wh, xlf, acc[ci][rg], 0, 0, 0);
                    acc[ci][rg] = MFMA16(wl, xhf, acc[ci][rg], 0, 0, 0);
                } else {        // D[xrow][wcol]
                    acc[ci][rg] = MFMA16(xhf, wh, acc[ci][rg], 0, 0, 0);
                    acc[ci][rg] = MFMA16(xlf, wh, acc[ci][rg], 0, 0, 0);
                    acc[ci][rg] = MFMA16(xhf, wl, acc[ci][rg], 0, 0, 0);
                }
            }
        }
    }

    // ---- f/g epilogue (global only; ct<4 lives on wave 0)
#pragma unroll
    for (int ci = 0; ci < 5; ci++) {
        const int ct = wv * 5 + ci;
        if (ct < 4) {
            const float* bias = (ct < 2) ? bfp : bgp;
            const int colbase = (ct & 1) * 16 + g * 4;
            float4 bv = *(const float4*)&bias[colbase];
#pragma unroll
            for (int rg = 0; rg < 4; rg++) {
                float v0 = acc[ci][rg][0] + bv.x, v1 = acc[ci][rg][1] + bv.y;
                float v2 = acc[ci][rg][2] + bv.z, v3 = acc[ci][rg][3] + bv.w;
                ushort h0 = bf16_rne(v0), h1 = bf16_rne(v1);
                ushort h2 = bf16_rne(v2), h3 = bf16_rne(v3);
                uint2 hw, lw;
                hw.x = (unsigned)h0 | ((unsigned)h1 << 16);
                hw.y = (unsigned)h2 | ((unsigned)h3 << 16);
                lw.x = (unsigned)bf16_rne(v0 - bf16_to_f(h0)) |
                       ((unsigned)bf16_rne(v1 - bf16_to_f(h1)) << 16);
                lw.y = (unsigned)bf16_rne(v2 - bf16_to_f(h2)) |
                       ((unsigned)bf16_rne(v3 - bf16_to_f(h3)) << 16);
                const size_t o = (size_t)(rowbase + rg * 16 + a) * 32 + colbase;
                if (ct < 2) { *(uint2*)&fh[o] = hw; *(uint2*)&fl[o] = lw; }
                else        { *(uint2*)&gh[o] = hw; *(uint2*)&gl[o] = lw; }
            }
        }
    }
    __syncthreads();   // all xh/xl reads done before hs overwrite

    // ---- h epilogue -> hs[c][n] transpose tile in LDS (pad 80)
#pragma unroll
    for (int ci = 0; ci < 5; ci++) {
        const int ct = wv * 5 + ci;
        if (ct >= 4) {
            const int c = (ct - 4) * 16 + a;
            const float bias = bhp[c];
#pragma unroll
            for (int rg = 0; rg < 4; rg++) {
                ushort h0 = bf16_rne(acc[ci][rg][0] + bias);
                ushort h1 = bf16_rne(acc[ci][rg][1] + bias);
                ushort h2 = bf16_rne(acc[ci][rg][2] + bias);
                ushort h3 = bf16_rne(acc[ci][rg][3] + bias);
                uint2 w;
                w.x = (unsigned)h0 | ((unsigned)h1 << 16);
                w.y = (unsigned)h2 | ((unsigned)h3 << 16);
                *(uint2*)&sbuf[c * 80 + rg * 16 + g * 4] = w;
            }
        }
    }
    __syncthreads();

    // ---- coalesced h^T store: 8 passes x (256 thr x 16B)
#pragma unroll
    for (int p = 0; p < 8; p++) {
        const int c = p * 32 + (tid >> 3);
        const int col = (tid & 7) * 8;
        u32x4 v = *(const u32x4*)&sbuf[c * 80 + col];
        *(u32x4*)&ht[(size_t)(bb * 256 + c) * 4096 + n0 + col] = v;
    }
}

// ---------------- Kernel 2: MFMA flash attention, 32 q-rows/wave -------------
// 256 blocks = (batch, 128-q tile); wave owns 2 q-groups -> every H/F LDS
// read feeds 2 MFMAs (halves LDS bytes, the measured bottleneck).
__global__ __launch_bounds__(256, 1) void attn_kernel(
    const ushort* __restrict__ fh, const ushort* __restrict__ fl,
    const ushort* __restrict__ gh, const ushort* __restrict__ gl,
    const ushort* __restrict__ ht, const float* __restrict__ x,
    const float* __restrict__ gammap, float* __restrict__ out)
{
    __shared__ __align__(16) ushort Fh[2][2048];
    __shared__ __align__(16) ushort Fl[2][2048];
    __shared__ __align__(16) ushort Hts[2][16384];

    const int tid = threadIdx.x;
    const int l = tid & 63, wv = tid >> 6;
    const int g = l >> 4, a = l & 15;
    const int bid = blockIdx.x;                       // 256 blocks
    const int swzb = ((bid & 7) << 5) + (bid >> 3);   // bijective XCD swizzle
    const int b = swzb >> 5;
    const int q0 = (swzb & 31) * 128;
    const int base = b * NN;

    // G fragments for both q-groups
    const size_t grow0 = (size_t)(base + q0 + wv * 32 + a) * CK_ + g * 8;
    const bf16x8 agh0 = *(const bf16x8*)(gh + grow0);
    const bf16x8 agl0 = *(const bf16x8*)(gl + grow0);
    const bf16x8 agh1 = *(const bf16x8*)(gh + grow0 + 16 * CK_);
    const bf16x8 agl1 = *(const bf16x8*)(gl + grow0 + 16 * CK_);

    float m0 = -1e30f, ls0 = 0.f, m1 = -1e30f, ls1 = 0.f;
    f32x4 acc0[16], acc1[16];
#pragma unroll
    for (int ct = 0; ct < 16; ct++) {
        acc0[ct] = (f32x4){0.f, 0.f, 0.f, 0.f};
        acc1[ct] = (f32x4){0.f, 0.f, 0.f, 0.f};
    }

    auto stage = [&](int buf, int kt) {
        const size_t frow = (size_t)(base + kt * 64 + wv * 16 + a) * CK_ + g * 8;
        gload16(fh + frow, &Fh[buf][wv * 512]);
        gload16(fl + frow, &Fl[buf][wv * 512]);
#pragma unroll
        for (int i = 0; i < 8; i++) {
            const int fr = wv * 8 + i;
            const int khh = fr >> 4, ct = fr & 15;
            const ushort* hsrc = ht + (size_t)(b * 256 + ct * 16 + a) * 4096
                                    + (size_t)(kt * 64 + khh * 32 + g * 8);
            gload16(hsrc, &Hts[buf][fr * 512]);
        }
    };

    stage(0, 0);
    __syncthreads();

    for (int kt = 0; kt < NN / 64; kt++) {
        const int cur = kt & 1;
        if (kt < NN / 64 - 1) stage(cur ^ 1, kt + 1);

        // ---- swapped QK^T, both q-groups share the F-fragment reads
        f32x4 s40[4], s41[4];
#pragma unroll
        for (int s = 0; s < 4; s++) {
            const bf16x8 bhk = *(const bf16x8*)&Fh[cur][(s * 64 + l) * 8];
            const bf16x8 blk = *(const bf16x8*)&Fl[cur][(s * 64 + l) * 8];
            f32x4 z0 = (f32x4){0.f, 0.f, 0.f, 0.f};
            z0 = MFMA16(bhk, agh0, z0, 0, 0, 0);
            z0 = MFMA16(blk, agh0, z0, 0, 0, 0);
            z0 = MFMA16(bhk, agl0, z0, 0, 0, 0);
            s40[s] = z0;
            f32x4 z1 = (f32x4){0.f, 0.f, 0.f, 0.f};
            z1 = MFMA16(bhk, agh1, z1, 0, 0, 0);
            z1 = MFMA16(blk, agh1, z1, 0, 0, 0);
            z1 = MFMA16(bhk, agl1, z1, 0, 0, 0);
            s41[s] = z1;
        }

        // ---- online softmax, per-lane query a, per group
        float pm0 = s40[0][0], pm1 = s41[0][0];
#pragma unroll
        for (int s = 0; s < 4; s++)
#pragma unroll
            for (int r = 0; r < 4; r++) {
                pm0 = fmaxf(pm0, s40[s][r]);
                pm1 = fmaxf(pm1, s41[s][r]);
            }
        pm0 = fmaxf(pm0, __shfl_xor(pm0, 16)); pm0 = fmaxf(pm0, __shfl_xor(pm0, 32));
        pm1 = fmaxf(pm1, __shfl_xor(pm1, 16)); pm1 = fmaxf(pm1, __shfl_xor(pm1, 32));

        const int defer = (pm0 <= m0 + 8.f) && (pm1 <= m1 + 8.f);
        if (!__all(defer)) {
            const float mn0 = fmaxf(m0, pm0), mn1 = fmaxf(m1, pm1);
            const float sc0 = __expf(m0 - mn0), sc1 = __expf(m1 - mn1);
            m0 = mn0; ls0 *= sc0; m1 = mn1; ls1 *= sc1;
            float scr0[4], scr1[4];
#pragma unroll
            for (int r = 0; r < 4; r++) {
                scr0[r] = __shfl(sc0, g * 4 + r);
                scr1[r] = __shfl(sc1, g * 4 + r);
            }
#pragma unroll
            for (int ct = 0; ct < 16; ct++)
#pragma unroll
                for (int r = 0; r < 4; r++) {
                    acc0[ct][r] *= scr0[r];
                    acc1[ct][r] *= scr1[r];
                }
        }

        float rs0 = 0.f, rs1 = 0.f;
        unsigned cw0[4][2], cw1[4][2];
#pragma unroll
        for (int s = 0; s < 4; s++) {
            float a0 = __expf(s40[s][0] - m0), a1 = __expf(s40[s][1] - m0);
            float a2 = __expf(s40[s][2] - m0), a3 = __expf(s40[s][3] - m0);
            rs0 += (a0 + a1) + (a2 + a3);
            cw0[s][0] = (unsigned)bf16_rne(a0) | ((unsigned)bf16_rne(a1) << 16);
            cw0[s][1] = (unsigned)bf16_rne(a2) | ((unsigned)bf16_rne(a3) << 16);
            float b0 = __expf(s41[s][0] - m1), b1 = __expf(s41[s][1] - m1);
            float b2 = __expf(s41[s][2] - m1), b3 = __expf(s41[s][3] - m1);
            rs1 += (b0 + b1) + (b2 + b3);
            cw1[s][0] = (unsigned)bf16_rne(b0) | ((unsigned)bf16_rne(b1) << 16);
            cw1[s][1] = (unsigned)bf16_rne(b2) | ((unsigned)bf16_rne(b3) << 16);
        }
        rs0 += __shfl_xor(rs0, 16); rs0 += __shfl_xor(rs0, 32); ls0 += rs0;
        rs1 += __shfl_xor(rs1, 16); rs1 += __shfl_xor(rs1, 32); ls1 += rs1;

        // ---- PV: each H-fragment read feeds BOTH q-groups' MFMAs
        const int src0 = ((g & 1) << 5) + a;
        const int src1 = src0 + 16;
        const int hi = g >> 1;
#pragma unroll
        for (int kh = 0; kh < 2; kh++) {
            const unsigned A0 = (unsigned)__shfl((int)cw0[kh * 2][0], src0);
            const unsigned A1 = (unsigned)__shfl((int)cw0[kh * 2][1], src0);
            const unsigned A2 = (unsigned)__shfl((int)cw0[kh * 2][0], src1);
            const unsigned A3 = (unsigned)__shfl((int)cw0[kh * 2][1], src1);
            const unsigned B0 = (unsigned)__shfl((int)cw0[kh * 2 + 1][0], src0);
            const unsigned B1 = (unsigned)__shfl((int)cw0[kh * 2 + 1][1], src0);
            const unsigned B2 = (unsigned)__shfl((int)cw0[kh * 2 + 1][0], src1);
            const unsigned B3 = (unsigned)__shfl((int)cw0[kh * 2 + 1][1], src1);
            u32x4 pw0;
            pw0[0] = hi ? B0 : A0; pw0[1] = hi ? B1 : A1;
            pw0[2] = hi ? B2 : A2; pw0[3] = hi ? B3 : A3;
            const bf16x8 pa0 = __builtin_bit_cast(bf16x8, pw0);

            const unsigned C0 = (unsigned)__shfl((int)cw1[kh * 2][0], src0);
            const unsigned C1 = (unsigned)__shfl((int)cw1[kh * 2][1], src0);
            const unsigned C2 = (unsigned)__shfl((int)cw1[kh * 2][0], src1);
            const unsigned C3 = (unsigned)__shfl((int)cw1[kh * 2][1], src1);
            const unsigned D0 = (unsigned)__shfl((int)cw1[kh * 2 + 1][0], src0);
            const unsigned D1 = (unsigned)__shfl((int)cw1[kh * 2 + 1][1], src0);
            const unsigned D2 = (unsigned)__shfl((int)cw1[kh * 2 + 1][0], src1);
            const unsigned D3 = (unsigned)__shfl((int)cw1[kh * 2 + 1][1], src1);
            u32x4 pw1;
            pw1[0] = hi ? D0 : C0; pw1[1] = hi ? D1 : C1;
            pw1[2] = hi ? D2 : C2; pw1[3] = hi ? D3 : C3;
            const bf16x8 pa1 = __builtin_bit_cast(bf16x8, pw1);

#pragma unroll
            for (int ct = 0; ct < 16; ct++) {
                const bf16x8 hb = *(const bf16x8*)&Hts[cur][((kh * 16 + ct) * 64 + l) * 8];
                acc0[ct] = MFMA16(pa0, hb, acc0[ct], 0, 0, 0);
                acc1[ct] = MFMA16(pa1, hb, acc1[ct], 0, 0, 0);
            }
        }

        __syncthreads();
    }

    // ---- epilogue: out = gamma * acc/l + x
    const float gamma = *gammap;
    const float inv0 = 1.f / ls0, inv1 = 1.f / ls1;
    float invr0[4], invr1[4];
#pragma unroll
    for (int r = 0; r < 4; r++) {
        invr0[r] = __shfl(inv0, g * 4 + r);
        invr1[r] = __shfl(inv1, g * 4 + r);
    }
#pragma unroll
    for (int ct = 0; ct < 16; ct++) {
#pragma unroll
        for (int r = 0; r < 4; r++) {
            const int row0 = base + q0 + wv * 32 + g * 4 + r;
            const int o0 = row0 * C_ + ct * 16 + a;
            out[o0] = fmaf(gamma, acc0[ct][r] * invr0[r], x[o0]);
            const int o1 = o0 + 16 * C_;
            out[o1] = fmaf(gamma, acc1[ct][r] * invr1[r], x[o1]);
        }
    }
}

extern "C" void kernel_launch(void* const* d_in, const int* in_sizes, int n_in,
                              void* d_out, int out_size, void* d_ws, size_t ws_size,
                              hipStream_t stream) {
    const float* x     = (const float*)d_in[0];
    const float* Wf    = (const float*)d_in[1];
    const float* bfp   = (const float*)d_in[2];
    const float* Wg    = (const float*)d_in[3];
    const float* bgp   = (const float*)d_in[4];
    const float* Wh    = (const float*)d_in[5];
    const float* bhp   = (const float*)d_in[6];
    const float* gamma = (const float*)d_in[7];
    float* out = (float*)d_out;

    const size_t npix = (size_t)B_ * NN;
    ushort* fh  = (ushort*)d_ws;             // [B*N][32] bf16 hi
    ushort* fl  = fh + npix * CK_;
    ushort* gh  = fl + npix * CK_;
    ushort* gl  = gh + npix * CK_;
    ushort* ht  = gl + npix * CK_;           // [B][256][4096] bf16 (h^T)
    ushort* whi = ht + (size_t)B_ * C_ * NN; // W fragments
    ushort* wlo = whi + 20 * 8 * 64 * 8;

    prep_kernel<<<320, 256, 0, stream>>>(Wf, Wg, Wh, whi, wlo);
    proj_kernel<<<(B_ * NN) / 64, 256, 0, stream>>>(x, whi, wlo, bfp, bgp, bhp,
                                                    fh, fl, gh, gl, ht);
    attn_kernel<<<B_ * (NN / 128), 256, 0, stream>>>(fh, fl, gh, gl, ht, x, gamma, out);
}